// Round 2
// baseline (1866.921 us; speedup 1.0000x reference)
//
#include <hip/hip_runtime.h>

// ---------------------------------------------------------------------------
// Problem constants: B=8, N=128, XD=256, ED=128, H=8, DF=32, FFX=1024, FFE=512
// All inputs/outputs are FLOAT32 (reference uses jnp.float32 throughout).
// Key identity: softmax over axis=1 followed by (attn * V[:,None]).sum(1)
// collapses to V exactly (softmax sums to 1 over the reduced axis), so the
// whole attention/softmax is skipped: newX = (x@wv+bv)@wxo+bxo.
// ---------------------------------------------------------------------------

#define RSQRT_DF 0.17677669529663687f  // 1/sqrt(32)

// out[M,N] = (relu?)(in[M,K] @ w[K,N] + bias[N]); all fp32.
// One thread per output element; w loads coalesced over n; in row broadcast.
__global__ __launch_bounds__(256) void gemm_f32(
    const float* __restrict__ in, const float* __restrict__ w,
    const float* __restrict__ bias, float* __restrict__ out,
    int M, int K, int N, int relu) {
    int idx = blockIdx.x * 256 + threadIdx.x;
    if (idx >= M * N) return;
    int m = idx / N, n = idx - m * N;
    const float* ir = in + (size_t)m * K;
    float acc = bias[n];
    for (int k = 0; k < K; ++k) acc = fmaf(ir[k], w[(size_t)k * N + n], acc);
    if (relu) acc = fmaxf(acc, 0.f);
    out[idx] = acc;
}

// LayerNorm over C=256: out = LN(a+addv)*g+beta. One block (256 thr) per row.
__global__ __launch_bounds__(256) void ln256_kernel(
    const float* __restrict__ a, const float* __restrict__ addv,
    const float* __restrict__ g, const float* __restrict__ beta,
    float* __restrict__ out) {
    int row = blockIdx.x, t = threadIdx.x;
    float v = a[row * 256 + t] + addv[row * 256 + t];
    float s1 = v, s2 = v * v;
    for (int off = 32; off; off >>= 1) {
        s1 += __shfl_down(s1, off);
        s2 += __shfl_down(s2, off);
    }
    __shared__ float w1[4], w2[4];
    __shared__ float mb, rb;
    int lane = t & 63, wid = t >> 6;
    if (lane == 0) { w1[wid] = s1; w2[wid] = s2; }
    __syncthreads();
    if (t == 0) {
        float S1 = w1[0] + w1[1] + w1[2] + w1[3];
        float S2 = w2[0] + w2[1] + w2[2] + w2[3];
        float mean = S1 * (1.f / 256.f);
        float var = S2 * (1.f / 256.f) - mean * mean;
        mb = mean;
        rb = rsqrtf(var + 1e-5f);
    }
    __syncthreads();
    out[row * 256 + t] = (v - mb) * rb * g[t] + beta[t];
}

// ---------------------------------------------------------------------------
// Fully fused e-path: one block (256 thr) handles 8 consecutive rows
// r = (b,i,j0..j0+7). All intermediates live in LDS; weights stream from L2.
// Stages: load -> E1/E2 -> Y -> newE -> LN -> h1(relu) -> h2 -> LN -> out.
// ---------------------------------------------------------------------------
__global__ __launch_bounds__(256) void epath_kernel(
    const float* __restrict__ e,
    const float* __restrict__ Qb, const float* __restrict__ Kb,
    const float* __restrict__ wem, const float* __restrict__ wea,
    const float* __restrict__ weo, const float* __restrict__ we1,
    const float* __restrict__ we2,
    const float* __restrict__ bem, const float* __restrict__ bea,
    const float* __restrict__ beo, const float* __restrict__ be1,
    const float* __restrict__ be2,
    const float* __restrict__ gne, const float* __restrict__ bne,
    float* __restrict__ eout) {
    __shared__ float lds[9472];  // 37.9 KB
    float* sE  = lds;            // [8][128]  e rows (kept for both residuals)
    float* sQ  = lds + 1024;     // [256]     Q row (b,i)
    float* sK  = lds + 1280;     // [8][256]  K rows (b,j)
    float* sY  = lds + 3328;     // [8][256]  Y rows
    float* sH1 = lds + 1280;     // [8][512]  aliases sK+sY (both dead by stage D)
    float* sP  = lds + 5376;     // [2][8][128] split-K partials
    float* sT  = lds + 7424;     // [8][128]  LN(e+newE)
    float* sR  = lds + 8448;     // [8][128]  combined newE / h2

    const int t = threadIdx.x;
    const int r0 = blockIdx.x * 8;     // 131072 rows total
    const int b = r0 >> 14;            // / (128*128)
    const int i = (r0 >> 7) & 127;
    const int j0 = r0 & 127;           // 8 | 128 -> same (b,i) for all 8 rows

    // ---- load e rows, Q row, K rows ----
    {
        const float* ep = e + (size_t)r0 * 128;
        for (int u = t; u < 1024; u += 256) sE[u] = ep[u];
        const float* qp = Qb + ((b << 7) + i) * 256;
        sQ[t] = qp[t];
        const float* kp = Kb + ((b << 7) + j0) * 256;
        for (int u = t; u < 2048; u += 256) sK[u] = kp[u];
    }
    __syncthreads();

    // ---- Stage B: E1,E2 then Y = (Q*K/sqrt(DF))*(E1+1)+E2 ; col c = t ----
    {
        float a1[8], a2[8];
#pragma unroll
        for (int r = 0; r < 8; ++r) { a1[r] = 0.f; a2[r] = 0.f; }
        for (int k = 0; k < 128; ++k) {
            float wm = wem[k * 256 + t];
            float wa = wea[k * 256 + t];
#pragma unroll
            for (int r = 0; r < 8; ++r) {
                float ev = sE[r * 128 + k];
                a1[r] = fmaf(ev, wm, a1[r]);
                a2[r] = fmaf(ev, wa, a2[r]);
            }
        }
        float bm = bem[t], ba = bea[t], qv = sQ[t];
#pragma unroll
        for (int r = 0; r < 8; ++r) {
            float qk = qv * sK[r * 256 + t] * RSQRT_DF;
            sY[r * 256 + t] = qk * (a1[r] + bm + 1.0f) + (a2[r] + ba);
        }
    }
    __syncthreads();

    const int c = t & 127, half = t >> 7;
    const int lane = t & 63, wid = t >> 6;

    // ---- Stage C: newE = Y @ weo + beo (split-K over 2 halves of 128) ----
    {
        float acc[8];
#pragma unroll
        for (int r = 0; r < 8; ++r) acc[r] = 0.f;
        const int kbase = half << 7;
        for (int kk = 0; kk < 128; ++kk) {
            int k = kbase + kk;
            float wv = weo[k * 128 + c];
#pragma unroll
            for (int r = 0; r < 8; ++r) acc[r] = fmaf(sY[r * 256 + k], wv, acc[r]);
        }
#pragma unroll
        for (int r = 0; r < 8; ++r) sP[((half << 3) + r) * 128 + c] = acc[r];
    }
    __syncthreads();
    for (int u = t; u < 1024; u += 256)
        sR[u] = sP[u] + sP[1024 + u] + beo[u & 127];
    __syncthreads();

    // ---- LN #1: sT = LN(e + newE)*gne + bne ; one wave per row ----
#pragma unroll
    for (int rr = wid; rr < 8; rr += 4) {
        float v0 = sE[rr * 128 + lane] + sR[rr * 128 + lane];
        float v1 = sE[rr * 128 + lane + 64] + sR[rr * 128 + lane + 64];
        float s1 = v0 + v1, s2 = v0 * v0 + v1 * v1;
        for (int off = 32; off; off >>= 1) {
            s1 += __shfl_down(s1, off);
            s2 += __shfl_down(s2, off);
        }
        s1 = __shfl(s1, 0); s2 = __shfl(s2, 0);
        float mean = s1 * 0.0078125f;
        float var = s2 * 0.0078125f - mean * mean;
        float rstd = rsqrtf(var + 1e-5f);
        sT[rr * 128 + lane]      = (v0 - mean) * rstd * gne[lane] + bne[lane];
        sT[rr * 128 + lane + 64] = (v1 - mean) * rstd * gne[lane + 64] + bne[lane + 64];
    }
    __syncthreads();

    // ---- Stage D: h1 = relu(sT @ we1 + be1); cols t and t+256 ----
    {
        float aA[8], aB[8];
#pragma unroll
        for (int r = 0; r < 8; ++r) { aA[r] = 0.f; aB[r] = 0.f; }
        for (int k = 0; k < 128; ++k) {
            float w0 = we1[k * 512 + t];
            float w1v = we1[k * 512 + t + 256];
#pragma unroll
            for (int r = 0; r < 8; ++r) {
                float tv = sT[r * 128 + k];
                aA[r] = fmaf(tv, w0, aA[r]);
                aB[r] = fmaf(tv, w1v, aB[r]);
            }
        }
        float b0 = be1[t], b1 = be1[t + 256];
#pragma unroll
        for (int r = 0; r < 8; ++r) {
            sH1[r * 512 + t]       = fmaxf(aA[r] + b0, 0.f);
            sH1[r * 512 + t + 256] = fmaxf(aB[r] + b1, 0.f);
        }
    }
    __syncthreads();

    // ---- Stage E: h2 = h1 @ we2 + be2 (split-K over 2 halves of 256) ----
    {
        float acc[8];
#pragma unroll
        for (int r = 0; r < 8; ++r) acc[r] = 0.f;
        const int kbase = half << 8;
        for (int kk = 0; kk < 256; ++kk) {
            int k = kbase + kk;
            float wv = we2[k * 128 + c];
#pragma unroll
            for (int r = 0; r < 8; ++r) acc[r] = fmaf(sH1[r * 512 + k], wv, acc[r]);
        }
#pragma unroll
        for (int r = 0; r < 8; ++r) sP[((half << 3) + r) * 128 + c] = acc[r];
    }
    __syncthreads();
    for (int u = t; u < 1024; u += 256)
        sR[u] = sP[u] + sP[1024 + u] + be2[u & 127];
    __syncthreads();

    // ---- LN #2: out = LN(e + h2)*gne + bne -> global f32 ----
#pragma unroll
    for (int rr = wid; rr < 8; rr += 4) {
        float v0 = sE[rr * 128 + lane] + sR[rr * 128 + lane];
        float v1 = sE[rr * 128 + lane + 64] + sR[rr * 128 + lane + 64];
        float s1 = v0 + v1, s2 = v0 * v0 + v1 * v1;
        for (int off = 32; off; off >>= 1) {
            s1 += __shfl_down(s1, off);
            s2 += __shfl_down(s2, off);
        }
        s1 = __shfl(s1, 0); s2 = __shfl(s2, 0);
        float mean = s1 * 0.0078125f;
        float var = s2 * 0.0078125f - mean * mean;
        float rstd = rsqrtf(var + 1e-5f);
        size_t o = (size_t)(r0 + rr) * 128;
        eout[o + lane]      = (v0 - mean) * rstd * gne[lane] + bne[lane];
        eout[o + lane + 64] = (v1 - mean) * rstd * gne[lane + 64] + bne[lane + 64];
    }
}

extern "C" void kernel_launch(void* const* d_in, const int* in_sizes, int n_in,
                              void* d_out, int out_size, void* d_ws, size_t ws_size,
                              hipStream_t stream) {
    // setup_inputs() order (all fp32):
    const float* x   = (const float*)d_in[0];
    const float* e   = (const float*)d_in[1];
    const float* wq  = (const float*)d_in[2];
    const float* wk  = (const float*)d_in[3];
    const float* wv  = (const float*)d_in[4];
    const float* wem = (const float*)d_in[5];
    const float* wea = (const float*)d_in[6];
    const float* wxo = (const float*)d_in[7];
    const float* weo = (const float*)d_in[8];
    const float* wx1 = (const float*)d_in[9];
    const float* wx2 = (const float*)d_in[10];
    const float* we1 = (const float*)d_in[11];
    const float* we2 = (const float*)d_in[12];
    const float* bq  = (const float*)d_in[13];
    const float* bk  = (const float*)d_in[14];
    const float* bv  = (const float*)d_in[15];
    const float* bem = (const float*)d_in[16];
    const float* bea = (const float*)d_in[17];
    const float* bxo = (const float*)d_in[18];
    const float* beo = (const float*)d_in[19];
    const float* bx1 = (const float*)d_in[20];
    const float* bx2 = (const float*)d_in[21];
    const float* be1 = (const float*)d_in[22];
    const float* be2 = (const float*)d_in[23];
    const float* gnx = (const float*)d_in[24];
    const float* bnx = (const float*)d_in[25];
    const float* gne = (const float*)d_in[26];
    const float* bne = (const float*)d_in[27];

    float* out = (float*)d_out;  // x_out (262144) then e_out (16777216)

    // fp32 workspace layout (10.5 MB)
    float* ws  = (float*)d_ws;
    float* Qb  = ws;              // 262144
    float* Kb  = Qb + 262144;     // 262144
    float* Vb  = Kb + 262144;     // 262144
    float* t1  = Vb + 262144;     // 262144  newX
    float* xt  = t1 + 262144;     // 262144  LN(x+newX)
    float* xh1 = xt + 262144;     // 1048576 relu(xt@wx1)
    float* xh2 = xh1 + 1048576;   // 262144  xh1@wx2

    gemm_f32<<<1024, 256, 0, stream>>>(x, wq, bq, Qb, 1024, 256, 256, 0);
    gemm_f32<<<1024, 256, 0, stream>>>(x, wk, bk, Kb, 1024, 256, 256, 0);
    gemm_f32<<<1024, 256, 0, stream>>>(x, wv, bv, Vb, 1024, 256, 256, 0);
    // wV == V (softmax collapses), so newX = V @ wxo + bxo
    gemm_f32<<<1024, 256, 0, stream>>>(Vb, wxo, bxo, t1, 1024, 256, 256, 0);
    ln256_kernel<<<1024, 256, 0, stream>>>(x, t1, gnx, bnx, xt);
    gemm_f32<<<4096, 256, 0, stream>>>(xt, wx1, bx1, xh1, 1024, 256, 1024, 1);
    gemm_f32<<<1024, 256, 0, stream>>>(xh1, wx2, bx2, xh2, 1024, 1024, 256, 0);
    ln256_kernel<<<1024, 256, 0, stream>>>(x, xh2, gnx, bnx, out);

    epath_kernel<<<16384, 256, 0, stream>>>(e, Qb, Kb, wem, wea, weo, we1, we2,
                                            bem, bea, beo, be1, be2, gne, bne,
                                            out + 262144);
}

// Round 4
// 437.536 us; speedup vs baseline: 4.2669x; 4.2669x over previous
//
#include <hip/hip_runtime.h>

// ---------------------------------------------------------------------------
// B=8, N=128, XD=256, ED=128, H=8, DF=32, FFX=1024, FFE=512. All I/O fp32.
// softmax over axis=1 + (attn*V).sum(1) collapses to V => newX = (x@wv+bv)@wxo+bxo.
// Compute strategy: bf16 MFMA (16x16x32) everywhere; fp32 accumulate.
//   A-frag: lane holds A[m=lane&15][k=(lane>>4)*8 + j], j=0..7 (16B contiguous)
//   B-frag: lane holds B[k=(lane>>4)*8+j][n=lane&15]  (pre-packed to contiguous)
//   C/D   : col=lane&15, row=(lane>>4)*4 + reg
// (All three verified by the passing x-path in round 3.)
// ---------------------------------------------------------------------------

#define RSQRT_DF 0.17677669529663687f  // 1/sqrt(32)

typedef __attribute__((ext_vector_type(8))) short short8;
typedef __attribute__((ext_vector_type(4))) short short4v;
typedef __attribute__((ext_vector_type(4))) float f32x4;

// fp32 -> bf16 bits, round-to-nearest-even
__device__ __forceinline__ short f2bs(float f) {
    unsigned u = __float_as_uint(f);
    unsigned r = u + 0x7FFFu + ((u >> 16) & 1u);
    return (short)(r >> 16);
}

// Pack W[K][N] fp32 -> bf16 B-fragment order:
// Wp[(((nt*(K/32)+kb)*64 + lane)*8 + j] = W[kb*32+(lane>>4)*8+j][nt*16+(lane&15)]
__global__ __launch_bounds__(256) void pack_w(const float* __restrict__ W,
                                              short* __restrict__ Wp, int K, int N) {
    int g = blockIdx.x * 256 + threadIdx.x;
    int kdiv = K >> 5;
    int total = (N >> 4) * kdiv * 64;
    if (g >= total) return;
    int lane = g & 63, rest = g >> 6;
    int kb = rest % kdiv, nt = rest / kdiv;
    int n = nt * 16 + (lane & 15);
    int k0 = kb * 32 + ((lane >> 4) << 3);
    short8 v;
#pragma unroll
    for (int j = 0; j < 8; ++j) v[j] = f2bs(W[(size_t)(k0 + j) * N + n]);
    *(short8*)(Wp + (size_t)g * 8) = v;
}

// Generic MFMA GEMM: out[M,N] = (relu?)(A[M,K] @ W + bias). A fp32, W packed bf16.
// grid = (M/32, N/256). Block: 256 thr, 4 waves; M-tile 32, N-tile 256, K-chunk 256.
__global__ __launch_bounds__(256, 2) void gemm_mfma(
    const float* __restrict__ A, const short* __restrict__ Wp,
    const float* __restrict__ bias, float* __restrict__ out,
    int M, int K, int N, int relu) {
    __shared__ short sA[32 * 264];  // +8 pad
    const int t = threadIdx.x, wave = t >> 6, lane = t & 63;
    const int quad = lane >> 4, l15 = lane & 15;
    const int m0 = blockIdx.x * 32;
    const int ntBase = blockIdx.y * 16;
    const int kdiv = K >> 5;
    f32x4 acc[8];
#pragma unroll
    for (int p = 0; p < 8; ++p) acc[p] = (f32x4){0.f, 0.f, 0.f, 0.f};

    for (int kc = 0; kc < K; kc += 256) {
        __syncthreads();
        for (int s = 0; s < 32; ++s)
            sA[s * 264 + t] = f2bs(A[(size_t)(m0 + s) * K + kc + t]);
        __syncthreads();
        for (int p = 0; p < 8; ++p) {
            int pos = wave * 8 + p, mt = pos >> 4, ntl = pos & 15;
            const short* aB = sA + (mt * 16 + l15) * 264 + quad * 8;
            const short* bB = Wp + ((size_t)((ntBase + ntl) * kdiv + (kc >> 5)) * 64 + lane) * 8;
#pragma unroll
            for (int kb = 0; kb < 8; ++kb) {
                short8 a = *(const short8*)(aB + kb * 32);
                short8 w = *(const short8*)(bB + (size_t)kb * 512);
                acc[p] = __builtin_amdgcn_mfma_f32_16x16x32_bf16(a, w, acc[p], 0, 0, 0);
            }
        }
    }
    for (int p = 0; p < 8; ++p) {
        int pos = wave * 8 + p, mt = pos >> 4, ntl = pos & 15;
        int col = (ntBase + ntl) * 16 + l15;
        float bv = bias[col];
#pragma unroll
        for (int r = 0; r < 4; ++r) {
            int row = m0 + mt * 16 + quad * 4 + r;
            float v = acc[p][r] + bv;
            if (relu) v = fmaxf(v, 0.f);
            out[(size_t)row * N + col] = v;
        }
    }
}

// LayerNorm over C=256: out = LN(a+addv)*g+beta. One block (256 thr) per row.
__global__ __launch_bounds__(256) void ln256_kernel(
    const float* __restrict__ a, const float* __restrict__ addv,
    const float* __restrict__ g, const float* __restrict__ beta,
    float* __restrict__ out) {
    int row = blockIdx.x, t = threadIdx.x;
    float v = a[row * 256 + t] + addv[row * 256 + t];
    float s1 = v, s2 = v * v;
    for (int off = 32; off; off >>= 1) {
        s1 += __shfl_down(s1, off);
        s2 += __shfl_down(s2, off);
    }
    __shared__ float w1[4], w2[4];
    __shared__ float mb, rb;
    int lane = t & 63, wid = t >> 6;
    if (lane == 0) { w1[wid] = s1; w2[wid] = s2; }
    __syncthreads();
    if (t == 0) {
        float S1 = w1[0] + w1[1] + w1[2] + w1[3];
        float S2 = w2[0] + w2[1] + w2[2] + w2[3];
        float mean = S1 * (1.f / 256.f);
        float var = S2 * (1.f / 256.f) - mean * mean;
        mb = mean;
        rb = rsqrtf(var + 1e-5f);
    }
    __syncthreads();
    out[row * 256 + t] = (v - mb) * rb * g[t] + beta[t];
}

// ---------------------------------------------------------------------------
// Fused MFMA e-path. Block = 256 thr (4 waves) handles 32 rows r0..r0+31,
// all sharing (b,i).
// LDS regions (bytes), NON-overlapping (round-3 bug: R2 started at 24576,
// clipping R1's last 512 bytes -> races on sEb/sTb rows 30-31 vs sQK/sR/sH1):
//  sEf @ 0      : 32*128*4 = 16384
//  R1  @ 16384  : 8704  = 32*136*2   (sEb -> sTb)
//  R2  @ 25088  : 33280 = max(sQK 32*260*4, sR 32*132*4, sH1 32*520*2)
//  R3  @ 58368  : 16896 = max(sYb 32*264*2, sH2 32*132*4)
//  total 75264 B -> 2 blocks/CU (150528 <= 163840)
// ---------------------------------------------------------------------------
__global__ __launch_bounds__(256, 2) void epath_mfma(
    const float* __restrict__ e,
    const float* __restrict__ Qb, const float* __restrict__ Kb,
    const short* __restrict__ wemP, const short* __restrict__ weaP,
    const short* __restrict__ weoP, const short* __restrict__ we1P,
    const short* __restrict__ we2P,
    const float* __restrict__ bem, const float* __restrict__ bea,
    const float* __restrict__ beo, const float* __restrict__ be1,
    const float* __restrict__ be2,
    const float* __restrict__ gne, const float* __restrict__ bne,
    float* __restrict__ eout) {
    __shared__ __align__(16) char ldsbuf[75264];
    float* sEf = (float*)ldsbuf;              // [32][128] fp32 residual copy
    short* sEb = (short*)(ldsbuf + 16384);    // [32][136] bf16 A-frags
    short* sTb = (short*)(ldsbuf + 16384);    // [32][136] (alias, after stage B)
    float* sQK = (float*)(ldsbuf + 25088);    // [32][260] q*k*rsqrt
    float* sR  = (float*)(ldsbuf + 25088);    // [32][132] (alias) newE
    short* sH1 = (short*)(ldsbuf + 25088);    // [32][520] (alias) relu-FF bf16
    short* sYb = (short*)(ldsbuf + 58368);    // [32][264] Y bf16
    float* sH2 = (float*)(ldsbuf + 58368);    // [32][132] (alias) FF2 out

    const int t = threadIdx.x, wave = t >> 6, lane = t & 63;
    const int quad = lane >> 4, l15 = lane & 15;
    const int r0 = blockIdx.x * 32;
    const int b = r0 >> 14;
    const int j0 = r0 & 127;  // 32 | 128 -> same (b,i) for the whole block

    // LN gamma/beta (reused by LN1 and LN2)
    float g0 = gne[lane], g1 = gne[lane + 64];
    float bn0 = bne[lane], bn1 = bne[lane + 64];

    // ---- load: e tile (fp32 + bf16), qk products ----
    {
        const float4* e4 = (const float4*)(e + (size_t)r0 * 128);
        for (int g = t; g < 1024; g += 256) {
            float4 v = e4[g];
            int row = g >> 5, col4 = (g & 31) * 4;
            *(float4*)(sEf + row * 128 + col4) = v;
            short4v sv = {f2bs(v.x), f2bs(v.y), f2bs(v.z), f2bs(v.w)};
            *(short4v*)(sEb + row * 136 + col4) = sv;
        }
        float qv = Qb[(size_t)(r0 >> 7) * 256 + t];  // row b*128+i, col t
        const float* kp = Kb + ((size_t)(b << 7) + j0) * 256;
        for (int s = 0; s < 32; ++s)
            sQK[s * 260 + t] = qv * kp[s * 256 + t] * RSQRT_DF;
    }
    __syncthreads();

    // ---- Stage B: E1/E2 MFMA + elementwise Y -> sYb ----
    for (int p = 0; p < 8; ++p) {
        int pos = wave * 8 + p, mt = pos >> 4, nt = pos & 15;
        f32x4 a1 = (f32x4){0.f, 0.f, 0.f, 0.f}, a2 = (f32x4){0.f, 0.f, 0.f, 0.f};
        const short* aB = sEb + (mt * 16 + l15) * 136 + quad * 8;
        const short* b1 = wemP + ((size_t)(nt * 4) * 64 + lane) * 8;
        const short* b2 = weaP + ((size_t)(nt * 4) * 64 + lane) * 8;
#pragma unroll
        for (int kb = 0; kb < 4; ++kb) {
            short8 a = *(const short8*)(aB + kb * 32);
            short8 w1 = *(const short8*)(b1 + kb * 512);
            short8 w2 = *(const short8*)(b2 + kb * 512);
            a1 = __builtin_amdgcn_mfma_f32_16x16x32_bf16(a, w1, a1, 0, 0, 0);
            a2 = __builtin_amdgcn_mfma_f32_16x16x32_bf16(a, w2, a2, 0, 0, 0);
        }
        int col = nt * 16 + l15;
        float bm = bem[col], ba = bea[col];
#pragma unroll
        for (int r = 0; r < 4; ++r) {
            int row = mt * 16 + quad * 4 + r;
            float y = sQK[row * 260 + col] * (a1[r] + bm + 1.0f) + (a2[r] + ba);
            sYb[row * 264 + col] = f2bs(y);
        }
    }
    __syncthreads();

    // ---- Stage C: newE = Y @ weo + beo -> sR ----
    for (int p = 0; p < 4; ++p) {
        int pos = wave * 4 + p, mt = pos >> 3, nt = pos & 7;
        f32x4 acc = (f32x4){0.f, 0.f, 0.f, 0.f};
        const short* aB = sYb + (mt * 16 + l15) * 264 + quad * 8;
        const short* bB = weoP + ((size_t)(nt * 8) * 64 + lane) * 8;
#pragma unroll
        for (int kb = 0; kb < 8; ++kb) {
            short8 a = *(const short8*)(aB + kb * 32);
            short8 w = *(const short8*)(bB + kb * 512);
            acc = __builtin_amdgcn_mfma_f32_16x16x32_bf16(a, w, acc, 0, 0, 0);
        }
        int col = nt * 16 + l15;
        float bo = beo[col];
#pragma unroll
        for (int r = 0; r < 4; ++r)
            sR[(mt * 16 + quad * 4 + r) * 132 + col] = acc[r] + bo;
    }
    __syncthreads();

    // ---- LN1: sTb = bf16(LN(e + newE)*gne + bne) ----
    for (int rr = 0; rr < 8; ++rr) {
        int row = wave * 8 + rr;
        float v0 = sEf[row * 128 + lane] + sR[row * 132 + lane];
        float v1 = sEf[row * 128 + lane + 64] + sR[row * 132 + lane + 64];
        float s1 = v0 + v1, s2 = v0 * v0 + v1 * v1;
        for (int off = 32; off; off >>= 1) {
            s1 += __shfl_down(s1, off);
            s2 += __shfl_down(s2, off);
        }
        s1 = __shfl(s1, 0); s2 = __shfl(s2, 0);
        float mean = s1 * 0.0078125f;
        float var = s2 * 0.0078125f - mean * mean;
        float rstd = rsqrtf(var + 1e-5f);
        sTb[row * 136 + lane]      = f2bs((v0 - mean) * rstd * g0 + bn0);
        sTb[row * 136 + lane + 64] = f2bs((v1 - mean) * rstd * g1 + bn1);
    }
    __syncthreads();

    // ---- Stage D: H1 = relu(T @ we1 + be1) -> sH1 bf16 ----
    for (int p = 0; p < 16; ++p) {
        int pos = wave * 16 + p, mt = pos >> 5, nt = pos & 31;
        f32x4 acc = (f32x4){0.f, 0.f, 0.f, 0.f};
        const short* aB = sTb + (mt * 16 + l15) * 136 + quad * 8;
        const short* bB = we1P + ((size_t)(nt * 4) * 64 + lane) * 8;
#pragma unroll
        for (int kb = 0; kb < 4; ++kb) {
            short8 a = *(const short8*)(aB + kb * 32);
            short8 w = *(const short8*)(bB + kb * 512);
            acc = __builtin_amdgcn_mfma_f32_16x16x32_bf16(a, w, acc, 0, 0, 0);
        }
        int col = nt * 16 + l15;
        float bv = be1[col];
#pragma unroll
        for (int r = 0; r < 4; ++r)
            sH1[(mt * 16 + quad * 4 + r) * 520 + col] = f2bs(fmaxf(acc[r] + bv, 0.f));
    }
    __syncthreads();

    // ---- Stage E: H2 = H1 @ we2 + be2 -> sH2 ----
    for (int p = 0; p < 4; ++p) {
        int pos = wave * 4 + p, mt = pos >> 3, nt = pos & 7;
        f32x4 acc = (f32x4){0.f, 0.f, 0.f, 0.f};
        const short* aB = sH1 + (mt * 16 + l15) * 520 + quad * 8;
        const short* bB = we2P + ((size_t)(nt * 16) * 64 + lane) * 8;
#pragma unroll
        for (int kb = 0; kb < 16; ++kb) {
            short8 a = *(const short8*)(aB + kb * 32);
            short8 w = *(const short8*)(bB + kb * 512);
            acc = __builtin_amdgcn_mfma_f32_16x16x32_bf16(a, w, acc, 0, 0, 0);
        }
        int col = nt * 16 + l15;
        float bv = be2[col];
#pragma unroll
        for (int r = 0; r < 4; ++r)
            sH2[(mt * 16 + quad * 4 + r) * 132 + col] = acc[r] + bv;
    }
    __syncthreads();

    // ---- LN2 -> global ----
    for (int rr = 0; rr < 8; ++rr) {
        int row = wave * 8 + rr;
        float v0 = sEf[row * 128 + lane] + sH2[row * 132 + lane];
        float v1 = sEf[row * 128 + lane + 64] + sH2[row * 132 + lane + 64];
        float s1 = v0 + v1, s2 = v0 * v0 + v1 * v1;
        for (int off = 32; off; off >>= 1) {
            s1 += __shfl_down(s1, off);
            s2 += __shfl_down(s2, off);
        }
        s1 = __shfl(s1, 0); s2 = __shfl(s2, 0);
        float mean = s1 * 0.0078125f;
        float var = s2 * 0.0078125f - mean * mean;
        float rstd = rsqrtf(var + 1e-5f);
        size_t o = (size_t)(r0 + row) * 128;
        eout[o + lane]      = (v0 - mean) * rstd * g0 + bn0;
        eout[o + lane + 64] = (v1 - mean) * rstd * g1 + bn1;
    }
}

extern "C" void kernel_launch(void* const* d_in, const int* in_sizes, int n_in,
                              void* d_out, int out_size, void* d_ws, size_t ws_size,
                              hipStream_t stream) {
    const float* x   = (const float*)d_in[0];
    const float* e   = (const float*)d_in[1];
    const float* wq  = (const float*)d_in[2];
    const float* wk  = (const float*)d_in[3];
    const float* wv  = (const float*)d_in[4];
    const float* wem = (const float*)d_in[5];
    const float* wea = (const float*)d_in[6];
    const float* wxo = (const float*)d_in[7];
    const float* weo = (const float*)d_in[8];
    const float* wx1 = (const float*)d_in[9];
    const float* wx2 = (const float*)d_in[10];
    const float* we1 = (const float*)d_in[11];
    const float* we2 = (const float*)d_in[12];
    const float* bq  = (const float*)d_in[13];
    const float* bk  = (const float*)d_in[14];
    const float* bv  = (const float*)d_in[15];
    const float* bem = (const float*)d_in[16];
    const float* bea = (const float*)d_in[17];
    const float* bxo = (const float*)d_in[18];
    const float* beo = (const float*)d_in[19];
    const float* bx1 = (const float*)d_in[20];
    const float* bx2 = (const float*)d_in[21];
    const float* be1 = (const float*)d_in[22];
    const float* be2 = (const float*)d_in[23];
    const float* gnx = (const float*)d_in[24];
    const float* bnx = (const float*)d_in[25];
    const float* gne = (const float*)d_in[26];
    const float* bne = (const float*)d_in[27];

    float* out = (float*)d_out;  // x_out (262144) then e_out (16777216)

    float* ws  = (float*)d_ws;
    float* Qb  = ws;              // 262144
    float* Kb  = Qb + 262144;     // 262144
    float* Vb  = Kb + 262144;     // 262144  (later aliased as xt)
    float* t1  = Vb + 262144;     // 262144  newX (later aliased as xh2)
    float* xh1 = t1 + 262144;     // 1048576
    float* xt  = Vb;              // alias: Vb dead after newX gemm
    float* xh2 = t1;              // alias: t1 dead after LN1

    short* wsS  = (short*)(xh1 + 1048576);
    short* wqP  = wsS;            // 65536
    short* wkP  = wqP + 65536;
    short* wvP  = wkP + 65536;
    short* wxoP = wvP + 65536;
    short* wx1P = wxoP + 65536;   // 262144
    short* wx2P = wx1P + 262144;  // 262144
    short* wemP = wx2P + 262144;  // 32768
    short* weaP = wemP + 32768;
    short* weoP = weaP + 32768;
    short* we1P = weoP + 32768;   // 65536
    short* we2P = we1P + 65536;   // 65536

    pack_w<<<32, 256, 0, stream>>>(wq, wqP, 256, 256);
    pack_w<<<32, 256, 0, stream>>>(wk, wkP, 256, 256);
    pack_w<<<32, 256, 0, stream>>>(wv, wvP, 256, 256);
    pack_w<<<32, 256, 0, stream>>>(wxo, wxoP, 256, 256);
    pack_w<<<128, 256, 0, stream>>>(wx1, wx1P, 256, 1024);
    pack_w<<<128, 256, 0, stream>>>(wx2, wx2P, 1024, 256);
    pack_w<<<16, 256, 0, stream>>>(wem, wemP, 128, 256);
    pack_w<<<16, 256, 0, stream>>>(wea, weaP, 128, 256);
    pack_w<<<16, 256, 0, stream>>>(weo, weoP, 256, 128);
    pack_w<<<32, 256, 0, stream>>>(we1, we1P, 128, 512);
    pack_w<<<32, 256, 0, stream>>>(we2, we2P, 512, 128);

    dim3 g32(32, 1), g32x4(32, 4);
    gemm_mfma<<<g32, 256, 0, stream>>>(x, wqP, bq, Qb, 1024, 256, 256, 0);
    gemm_mfma<<<g32, 256, 0, stream>>>(x, wkP, bk, Kb, 1024, 256, 256, 0);
    gemm_mfma<<<g32, 256, 0, stream>>>(x, wvP, bv, Vb, 1024, 256, 256, 0);
    gemm_mfma<<<g32, 256, 0, stream>>>(Vb, wxoP, bxo, t1, 1024, 256, 256, 0);
    ln256_kernel<<<1024, 256, 0, stream>>>(x, t1, gnx, bnx, xt);
    gemm_mfma<<<g32x4, 256, 0, stream>>>(xt, wx1P, bx1, xh1, 1024, 256, 1024, 1);
    gemm_mfma<<<g32, 256, 0, stream>>>(xh1, wx2P, bx2, xh2, 1024, 1024, 256, 0);
    ln256_kernel<<<1024, 256, 0, stream>>>(x, xh2, gnx, bnx, out);

    epath_mfma<<<4096, 256, 0, stream>>>(e, Qb, Kb, wemP, weaP, weoP, we1P, we2P,
                                         bem, bea, beo, be1, be2, gne, bne,
                                         out + 262144);
}

// Round 5
// 387.785 us; speedup vs baseline: 4.8143x; 1.1283x over previous
//
#include <hip/hip_runtime.h>

// ---------------------------------------------------------------------------
// B=8, N=128, XD=256, ED=128, H=8, DF=32, FFX=1024, FFE=512. All I/O fp32.
// softmax over axis=1 + (attn*V).sum(1) collapses to V => newX = (x@wv+bv)@wxo+bxo.
// bf16 MFMA 16x16x32 everywhere; fp32 accumulate. Verified layouts (round 3/4):
//   A-frag: lane holds A[m=lane&15][k=(lane>>4)*8 + j], j=0..7
//   B-frag: lane holds B[k=(lane>>4)*8+j][n=lane&15]  (pre-packed contiguous)
//   C/D   : col=lane&15, row=(lane>>4)*4 + reg
// Round 5: 3 launches total (pack_all, xpath_fused, epath_mfma);
// epath LDS 75264->52224 B for 3 blocks/CU.
// ---------------------------------------------------------------------------

#define RSQRT_DF 0.17677669529663687f  // 1/sqrt(32)

typedef __attribute__((ext_vector_type(8))) short short8;
typedef __attribute__((ext_vector_type(4))) short short4v;
typedef __attribute__((ext_vector_type(4))) float f32x4;

__device__ __forceinline__ short f2bs(float f) {  // fp32->bf16 bits, RNE
    unsigned u = __float_as_uint(f);
    unsigned r = u + 0x7FFFu + ((u >> 16) & 1u);
    return (short)(r >> 16);
}
__device__ __forceinline__ float bs2f(short s) {  // bf16 bits->fp32
    return __uint_as_float(((unsigned)(unsigned short)s) << 16);
}

// ---------------- single-launch weight pack (all 11 weights) ----------------
struct PackArgs {
    const float* W[11];
    short* Wp[11];
    int kdiv[11];   // K/32
    int N[11];
    int start[12];  // prefix sums of per-weight group counts; start[11]=total
};

__global__ __launch_bounds__(256) void pack_all(PackArgs pa) {
    int g = blockIdx.x * 256 + threadIdx.x;
    if (g >= pa.start[11]) return;
    int i = 0;
    while (g >= pa.start[i + 1]) ++i;
    int local = g - pa.start[i];
    int kdiv = pa.kdiv[i], N = pa.N[i];
    int lane = local & 63, rest = local >> 6;
    int kb = rest % kdiv, nt = rest / kdiv;
    int n = nt * 16 + (lane & 15);
    int k0 = kb * 32 + ((lane >> 4) << 3);
    const float* W = pa.W[i];
    short8 v;
#pragma unroll
    for (int j = 0; j < 8; ++j) v[j] = f2bs(W[(size_t)(k0 + j) * N + n]);
    *(short8*)(pa.Wp[i] + (size_t)local * 8) = v;
}

// ---------------- fully fused x-path -----------------------------------
// 64 blocks x 16 rows. Q=x@wq+bq, K=x@wk+bk (both -> global for epath),
// V=x@wv+bv, newX=V@wxo+bxo, LN, H1=relu(.@wx1+bx1), H2=.@wx2+bx2, LN -> out.
__global__ __launch_bounds__(256) void xpath_fused(
    const float* __restrict__ x,
    const short* __restrict__ wqP, const short* __restrict__ wkP,
    const short* __restrict__ wvP, const short* __restrict__ wxoP,
    const short* __restrict__ wx1P, const short* __restrict__ wx2P,
    const float* __restrict__ bq, const float* __restrict__ bk,
    const float* __restrict__ bv, const float* __restrict__ bxo,
    const float* __restrict__ bx1, const float* __restrict__ bx2,
    const float* __restrict__ gnx, const float* __restrict__ bnx,
    float* __restrict__ Qb, float* __restrict__ Kb,
    float* __restrict__ xout) {
    __shared__ __align__(16) char ldsbuf[91392];
    float* sXf = (float*)ldsbuf;               // [16][256] f32 residual
    short* sXb = (short*)(ldsbuf + 16384);     // [16][264] bf16 A-frag
    short* sVb = (short*)(ldsbuf + 24832);     // [16][264]
    float* sR  = (float*)(ldsbuf + 33280);     // [16][260] newX
    float* sH2 = (float*)(ldsbuf + 33280);     // alias (sR dead after LN1)
    short* sTb = (short*)(ldsbuf + 49920);     // [16][264]
    short* sH1 = (short*)(ldsbuf + 58368);     // [16][1032]

    const int t = threadIdx.x, wave = t >> 6, lane = t & 63;
    const int quad = lane >> 4, l15 = lane & 15;
    const int m0 = blockIdx.x * 16;

    // ---- load x tile ----
    {
        const float4* x4 = (const float4*)(x + (size_t)m0 * 256);
        for (int g = t; g < 1024; g += 256) {
            float4 v = x4[g];
            int row = g >> 6, col4 = (g & 63) * 4;
            *(float4*)(sXf + row * 256 + col4) = v;
            short4v sv = {f2bs(v.x), f2bs(v.y), f2bs(v.z), f2bs(v.w)};
            *(short4v*)(sXb + row * 264 + col4) = sv;
        }
    }
    __syncthreads();

    // ---- QKV: 48 tiles (Q:0-15, K:16-31, V:32-47), M=16 so mt=0 ----
    for (int p = 0; p < 12; ++p) {
        int pos = wave * 12 + p;
        int sel = pos >> 4, nt = pos & 15;
        const short* wP = (sel == 0) ? wqP : (sel == 1) ? wkP : wvP;
        f32x4 acc = (f32x4){0.f, 0.f, 0.f, 0.f};
        const short* aB = sXb + l15 * 264 + quad * 8;
        const short* bB = wP + ((size_t)(nt * 8) * 64 + lane) * 8;
#pragma unroll
        for (int kb = 0; kb < 8; ++kb) {
            short8 a = *(const short8*)(aB + kb * 32);
            short8 w = *(const short8*)(bB + (size_t)kb * 512);
            acc = __builtin_amdgcn_mfma_f32_16x16x32_bf16(a, w, acc, 0, 0, 0);
        }
        int col = nt * 16 + l15;
        if (sel == 0) {
            float bvv = bq[col];
#pragma unroll
            for (int r = 0; r < 4; ++r)
                Qb[(size_t)(m0 + quad * 4 + r) * 256 + col] = acc[r] + bvv;
        } else if (sel == 1) {
            float bvv = bk[col];
#pragma unroll
            for (int r = 0; r < 4; ++r)
                Kb[(size_t)(m0 + quad * 4 + r) * 256 + col] = acc[r] + bvv;
        } else {
            float bvv = bv[col];
#pragma unroll
            for (int r = 0; r < 4; ++r)
                sVb[(quad * 4 + r) * 264 + col] = f2bs(acc[r] + bvv);
        }
    }
    __syncthreads();

    // ---- newX = V @ wxo + bxo -> sR ----
    for (int p = 0; p < 4; ++p) {
        int nt = wave * 4 + p;
        f32x4 acc = (f32x4){0.f, 0.f, 0.f, 0.f};
        const short* aB = sVb + l15 * 264 + quad * 8;
        const short* bB = wxoP + ((size_t)(nt * 8) * 64 + lane) * 8;
#pragma unroll
        for (int kb = 0; kb < 8; ++kb) {
            short8 a = *(const short8*)(aB + kb * 32);
            short8 w = *(const short8*)(bB + (size_t)kb * 512);
            acc = __builtin_amdgcn_mfma_f32_16x16x32_bf16(a, w, acc, 0, 0, 0);
        }
        int col = nt * 16 + l15;
        float bvv = bxo[col];
#pragma unroll
        for (int r = 0; r < 4; ++r)
            sR[(quad * 4 + r) * 260 + col] = acc[r] + bvv;
    }
    __syncthreads();

    // ---- LN1 -> sTb bf16 ----
    for (int rr = 0; rr < 4; ++rr) {
        int row = wave * 4 + rr;
        float v[4];
        float s1 = 0.f, s2 = 0.f;
#pragma unroll
        for (int k = 0; k < 4; ++k) {
            v[k] = sXf[row * 256 + lane + 64 * k] + sR[row * 260 + lane + 64 * k];
            s1 += v[k]; s2 += v[k] * v[k];
        }
        for (int off = 32; off; off >>= 1) {
            s1 += __shfl_down(s1, off);
            s2 += __shfl_down(s2, off);
        }
        s1 = __shfl(s1, 0); s2 = __shfl(s2, 0);
        float mean = s1 * (1.f / 256.f);
        float var = s2 * (1.f / 256.f) - mean * mean;
        float rstd = rsqrtf(var + 1e-5f);
#pragma unroll
        for (int k = 0; k < 4; ++k)
            sTb[row * 264 + lane + 64 * k] =
                f2bs((v[k] - mean) * rstd * gnx[lane + 64 * k] + bnx[lane + 64 * k]);
    }
    __syncthreads();

    // ---- H1 = relu(T @ wx1 + bx1) -> sH1 (N=1024, 64 tiles) ----
    for (int p = 0; p < 16; ++p) {
        int nt = wave * 16 + p;
        f32x4 acc = (f32x4){0.f, 0.f, 0.f, 0.f};
        const short* aB = sTb + l15 * 264 + quad * 8;
        const short* bB = wx1P + ((size_t)(nt * 8) * 64 + lane) * 8;
#pragma unroll
        for (int kb = 0; kb < 8; ++kb) {
            short8 a = *(const short8*)(aB + kb * 32);
            short8 w = *(const short8*)(bB + (size_t)kb * 512);
            acc = __builtin_amdgcn_mfma_f32_16x16x32_bf16(a, w, acc, 0, 0, 0);
        }
        int col = nt * 16 + l15;
        float bvv = bx1[col];
#pragma unroll
        for (int r = 0; r < 4; ++r)
            sH1[(quad * 4 + r) * 1032 + col] = f2bs(fmaxf(acc[r] + bvv, 0.f));
    }
    __syncthreads();

    // ---- H2 = H1 @ wx2 + bx2 -> sH2 (K=1024, 32 kb) ----
    for (int p = 0; p < 4; ++p) {
        int nt = wave * 4 + p;
        f32x4 acc = (f32x4){0.f, 0.f, 0.f, 0.f};
        const short* aB = sH1 + l15 * 1032 + quad * 8;
        const short* bB = wx2P + ((size_t)(nt * 32) * 64 + lane) * 8;
#pragma unroll
        for (int kb = 0; kb < 32; ++kb) {
            short8 a = *(const short8*)(aB + kb * 32);
            short8 w = *(const short8*)(bB + (size_t)kb * 512);
            acc = __builtin_amdgcn_mfma_f32_16x16x32_bf16(a, w, acc, 0, 0, 0);
        }
        int col = nt * 16 + l15;
        float bvv = bx2[col];
#pragma unroll
        for (int r = 0; r < 4; ++r)
            sH2[(quad * 4 + r) * 260 + col] = acc[r] + bvv;
    }
    __syncthreads();

    // ---- LN2 -> xout ----
    for (int rr = 0; rr < 4; ++rr) {
        int row = wave * 4 + rr;
        float v[4];
        float s1 = 0.f, s2 = 0.f;
#pragma unroll
        for (int k = 0; k < 4; ++k) {
            v[k] = sXf[row * 256 + lane + 64 * k] + sH2[row * 260 + lane + 64 * k];
            s1 += v[k]; s2 += v[k] * v[k];
        }
        for (int off = 32; off; off >>= 1) {
            s1 += __shfl_down(s1, off);
            s2 += __shfl_down(s2, off);
        }
        s1 = __shfl(s1, 0); s2 = __shfl(s2, 0);
        float mean = s1 * (1.f / 256.f);
        float var = s2 * (1.f / 256.f) - mean * mean;
        float rstd = rsqrtf(var + 1e-5f);
#pragma unroll
        for (int k = 0; k < 4; ++k)
            xout[(size_t)(m0 + row) * 256 + lane + 64 * k] =
                (v[k] - mean) * rstd * gnx[lane + 64 * k] + bnx[lane + 64 * k];
    }
}

// ---------------- fused MFMA e-path (v2: 52224 B LDS, 3 blocks/CU) ---------
// Block = 256 thr / 4 waves, 32 rows sharing (b,i). e residual kept in bf16.
// QK computed on the fly in stage-B epilogue (K from L2-resident Kb).
// FF split into two k-halves so H1 buffer is [32][264] instead of [32][520].
// LDS: sEb@0 8704 | sTb@8704 8704 | R2@17408 16896 (sR -> sH1half) |
//      R3@34304 16896 (sYb -> sH2) | sQ@51200 1024  => 52224 B
__global__ __launch_bounds__(256, 3) void epath_mfma(
    const float* __restrict__ e,
    const float* __restrict__ Qb, const float* __restrict__ Kb,
    const short* __restrict__ wemP, const short* __restrict__ weaP,
    const short* __restrict__ weoP, const short* __restrict__ we1P,
    const short* __restrict__ we2P,
    const float* __restrict__ bem, const float* __restrict__ bea,
    const float* __restrict__ beo, const float* __restrict__ be1,
    const float* __restrict__ be2,
    const float* __restrict__ gne, const float* __restrict__ bne,
    float* __restrict__ eout) {
    __shared__ __align__(16) char ldsbuf[52224];
    short* sEb = (short*)ldsbuf;               // [32][136] bf16 e (A-frag + residual)
    short* sTb = (short*)(ldsbuf + 8704);      // [32][136] LN1 out
    float* sR  = (float*)(ldsbuf + 17408);     // [32][132] newE
    short* sH1 = (short*)(ldsbuf + 17408);     // [32][264] (alias) H1 half
    short* sYb = (short*)(ldsbuf + 34304);     // [32][264] Y bf16
    float* sH2 = (float*)(ldsbuf + 34304);     // [32][132] (alias) FF2 out
    float* sQ  = (float*)(ldsbuf + 51200);     // [256] Q row fp32

    const int t = threadIdx.x, wave = t >> 6, lane = t & 63;
    const int quad = lane >> 4, l15 = lane & 15;
    const int r0 = blockIdx.x * 32;
    const int b = r0 >> 14;
    const int j0 = r0 & 127;  // 32 | 128 -> same (b,i) for the whole block

    float g0 = gne[lane], g1 = gne[lane + 64];
    float bn0 = bne[lane], bn1 = bne[lane + 64];

    // ---- load e tile (bf16) + Q row ----
    {
        const float4* e4 = (const float4*)(e + (size_t)r0 * 128);
        for (int g = t; g < 1024; g += 256) {
            float4 v = e4[g];
            int row = g >> 5, col4 = (g & 31) * 4;
            short4v sv = {f2bs(v.x), f2bs(v.y), f2bs(v.z), f2bs(v.w)};
            *(short4v*)(sEb + row * 136 + col4) = sv;
        }
        sQ[t] = Qb[(size_t)(r0 >> 7) * 256 + t];
    }
    __syncthreads();

    // ---- Stage B: E1/E2 MFMA; Y = (q*k/sqrt(DF))*(E1+1)+E2 -> sYb ----
    for (int p = 0; p < 8; ++p) {
        int pos = wave * 8 + p, mt = pos >> 4, nt = pos & 15;
        f32x4 a1 = (f32x4){0.f, 0.f, 0.f, 0.f}, a2 = (f32x4){0.f, 0.f, 0.f, 0.f};
        const short* aB = sEb + (mt * 16 + l15) * 136 + quad * 8;
        const short* b1 = wemP + ((size_t)(nt * 4) * 64 + lane) * 8;
        const short* b2 = weaP + ((size_t)(nt * 4) * 64 + lane) * 8;
#pragma unroll
        for (int kb = 0; kb < 4; ++kb) {
            short8 a = *(const short8*)(aB + kb * 32);
            short8 w1 = *(const short8*)(b1 + kb * 512);
            short8 w2 = *(const short8*)(b2 + kb * 512);
            a1 = __builtin_amdgcn_mfma_f32_16x16x32_bf16(a, w1, a1, 0, 0, 0);
            a2 = __builtin_amdgcn_mfma_f32_16x16x32_bf16(a, w2, a2, 0, 0, 0);
        }
        int col = nt * 16 + l15;
        float qv = sQ[col] * RSQRT_DF;
        float bm = bem[col], ba = bea[col];
        const float* kcol =
            Kb + ((size_t)((b << 7) + j0 + mt * 16 + quad * 4)) * 256 + col;
#pragma unroll
        for (int r = 0; r < 4; ++r) {
            int row = mt * 16 + quad * 4 + r;
            float qk = qv * kcol[(size_t)r * 256];
            float y = qk * (a1[r] + bm + 1.0f) + (a2[r] + ba);
            sYb[row * 264 + col] = f2bs(y);
        }
    }
    __syncthreads();

    // ---- Stage C: newE = Y @ weo + beo -> sR ----
    for (int p = 0; p < 4; ++p) {
        int pos = wave * 4 + p, mt = pos >> 3, nt = pos & 7;
        f32x4 acc = (f32x4){0.f, 0.f, 0.f, 0.f};
        const short* aB = sYb + (mt * 16 + l15) * 264 + quad * 8;
        const short* bB = weoP + ((size_t)(nt * 8) * 64 + lane) * 8;
#pragma unroll
        for (int kb = 0; kb < 8; ++kb) {
            short8 a = *(const short8*)(aB + kb * 32);
            short8 w = *(const short8*)(bB + kb * 512);
            acc = __builtin_amdgcn_mfma_f32_16x16x32_bf16(a, w, acc, 0, 0, 0);
        }
        int col = nt * 16 + l15;
        float bo = beo[col];
#pragma unroll
        for (int r = 0; r < 4; ++r)
            sR[(mt * 16 + quad * 4 + r) * 132 + col] = acc[r] + bo;
    }
    __syncthreads();

    // ---- LN1: sTb = bf16(LN(e + newE)*gne + bne) ----
    for (int rr = 0; rr < 8; ++rr) {
        int row = wave * 8 + rr;
        float v0 = bs2f(sEb[row * 136 + lane]) + sR[row * 132 + lane];
        float v1 = bs2f(sEb[row * 136 + lane + 64]) + sR[row * 132 + lane + 64];
        float s1 = v0 + v1, s2 = v0 * v0 + v1 * v1;
        for (int off = 32; off; off >>= 1) {
            s1 += __shfl_down(s1, off);
            s2 += __shfl_down(s2, off);
        }
        s1 = __shfl(s1, 0); s2 = __shfl(s2, 0);
        float mean = s1 * 0.0078125f;
        float var = s2 * 0.0078125f - mean * mean;
        float rstd = rsqrtf(var + 1e-5f);
        sTb[row * 136 + lane]      = f2bs((v0 - mean) * rstd * g0 + bn0);
        sTb[row * 136 + lane + 64] = f2bs((v1 - mean) * rstd * g1 + bn1);
    }
    __syncthreads();

    // ---- FF: two k-halves. D-half writes sH1 [32][264]; E accumulates. ----
    f32x4 accE[4];
#pragma unroll
    for (int p = 0; p < 4; ++p) accE[p] = (f32x4){0.f, 0.f, 0.f, 0.f};

    for (int half = 0; half < 2; ++half) {
        // D-half: H1 cols [half*256, half*256+256) ; 32 tiles
        for (int p = 0; p < 8; ++p) {
            int pos = wave * 8 + p, mt = pos >> 4, ntl = pos & 15;
            int nt = half * 16 + ntl;
            f32x4 acc = (f32x4){0.f, 0.f, 0.f, 0.f};
            const short* aB = sTb + (mt * 16 + l15) * 136 + quad * 8;
            const short* bB = we1P + ((size_t)(nt * 4) * 64 + lane) * 8;
#pragma unroll
            for (int kb = 0; kb < 4; ++kb) {
                short8 a = *(const short8*)(aB + kb * 32);
                short8 w = *(const short8*)(bB + kb * 512);
                acc = __builtin_amdgcn_mfma_f32_16x16x32_bf16(a, w, acc, 0, 0, 0);
            }
            int coll = ntl * 16 + l15;
            float bvv = be1[nt * 16 + l15];
#pragma unroll
            for (int r = 0; r < 4; ++r)
                sH1[(mt * 16 + quad * 4 + r) * 264 + coll] =
                    f2bs(fmaxf(acc[r] + bvv, 0.f));
        }
        __syncthreads();
        // E-half: accumulate k in [half*256, half*256+256)
        for (int p = 0; p < 4; ++p) {
            int pos = wave * 4 + p, mt = pos >> 3, nt = pos & 7;
            const short* aB = sH1 + (mt * 16 + l15) * 264 + quad * 8;
            const short* bB =
                we2P + ((size_t)(nt * 16 + half * 8) * 64 + lane) * 8;
#pragma unroll
            for (int kb = 0; kb < 8; ++kb) {
                short8 a = *(const short8*)(aB + kb * 32);
                short8 w = *(const short8*)(bB + kb * 512);
                accE[p] = __builtin_amdgcn_mfma_f32_16x16x32_bf16(a, w, accE[p], 0, 0, 0);
            }
        }
        __syncthreads();
    }
    // E epilogue -> sH2
    for (int p = 0; p < 4; ++p) {
        int pos = wave * 4 + p, mt = pos >> 3, nt = pos & 7;
        int col = nt * 16 + l15;
        float bvv = be2[col];
#pragma unroll
        for (int r = 0; r < 4; ++r)
            sH2[(mt * 16 + quad * 4 + r) * 132 + col] = accE[p][r] + bvv;
    }
    __syncthreads();

    // ---- LN2 -> global ----
    for (int rr = 0; rr < 8; ++rr) {
        int row = wave * 8 + rr;
        float v0 = bs2f(sEb[row * 136 + lane]) + sH2[row * 132 + lane];
        float v1 = bs2f(sEb[row * 136 + lane + 64]) + sH2[row * 132 + lane + 64];
        float s1 = v0 + v1, s2 = v0 * v0 + v1 * v1;
        for (int off = 32; off; off >>= 1) {
            s1 += __shfl_down(s1, off);
            s2 += __shfl_down(s2, off);
        }
        s1 = __shfl(s1, 0); s2 = __shfl(s2, 0);
        float mean = s1 * 0.0078125f;
        float var = s2 * 0.0078125f - mean * mean;
        float rstd = rsqrtf(var + 1e-5f);
        size_t o = (size_t)(r0 + row) * 128;
        eout[o + lane]      = (v0 - mean) * rstd * g0 + bn0;
        eout[o + lane + 64] = (v1 - mean) * rstd * g1 + bn1;
    }
}

extern "C" void kernel_launch(void* const* d_in, const int* in_sizes, int n_in,
                              void* d_out, int out_size, void* d_ws, size_t ws_size,
                              hipStream_t stream) {
    const float* x   = (const float*)d_in[0];
    const float* e   = (const float*)d_in[1];
    const float* wq  = (const float*)d_in[2];
    const float* wk  = (const float*)d_in[3];
    const float* wv  = (const float*)d_in[4];
    const float* wem = (const float*)d_in[5];
    const float* wea = (const float*)d_in[6];
    const float* wxo = (const float*)d_in[7];
    const float* weo = (const float*)d_in[8];
    const float* wx1 = (const float*)d_in[9];
    const float* wx2 = (const float*)d_in[10];
    const float* we1 = (const float*)d_in[11];
    const float* we2 = (const float*)d_in[12];
    const float* bq  = (const float*)d_in[13];
    const float* bk  = (const float*)d_in[14];
    const float* bv  = (const float*)d_in[15];
    const float* bem = (const float*)d_in[16];
    const float* bea = (const float*)d_in[17];
    const float* bxo = (const float*)d_in[18];
    const float* beo = (const float*)d_in[19];
    const float* bx1 = (const float*)d_in[20];
    const float* bx2 = (const float*)d_in[21];
    const float* be1 = (const float*)d_in[22];
    const float* be2 = (const float*)d_in[23];
    const float* gnx = (const float*)d_in[24];
    const float* bnx = (const float*)d_in[25];
    const float* gne = (const float*)d_in[26];
    const float* bne = (const float*)d_in[27];

    float* out = (float*)d_out;  // x_out (262144) then e_out (16777216)

    float* ws = (float*)d_ws;
    float* Qb = ws;               // 262144 f32
    float* Kb = Qb + 262144;      // 262144 f32
    short* base = (short*)(Kb + 262144);
    short* wqP  = base;           // 65536
    short* wkP  = wqP + 65536;
    short* wvP  = wkP + 65536;
    short* wxoP = wvP + 65536;
    short* wx1P = wxoP + 65536;   // 262144
    short* wx2P = wx1P + 262144;  // 262144
    short* wemP = wx2P + 262144;  // 32768
    short* weaP = wemP + 32768;
    short* weoP = weaP + 32768;
    short* we1P = weoP + 32768;   // 65536
    short* we2P = we1P + 65536;   // 65536

    // ---- one pack launch for all 11 weights ----
    PackArgs pa;
    const float* Ws[11] = {wq, wk, wv, wxo, wx1, wx2, wem, wea, weo, we1, we2};
    short* Wps[11] = {wqP, wkP, wvP, wxoP, wx1P, wx2P, wemP, weaP, weoP, we1P, we2P};
    int Ks[11] = {256, 256, 256, 256, 256, 1024, 128, 128, 256, 128, 512};
    int Ns[11] = {256, 256, 256, 256, 1024, 256, 256, 256, 128, 512, 128};
    int acc = 0;
    for (int i = 0; i < 11; ++i) {
        pa.W[i] = Ws[i];
        pa.Wp[i] = Wps[i];
        pa.kdiv[i] = Ks[i] >> 5;
        pa.N[i] = Ns[i];
        pa.start[i] = acc;
        acc += (Ns[i] >> 4) * (Ks[i] >> 5) * 64;
    }
    pa.start[11] = acc;  // 126976 -> 496 blocks
    pack_all<<<(acc + 255) / 256, 256, 0, stream>>>(pa);

    // ---- fused x-path (also produces Qb, Kb for the e-path) ----
    xpath_fused<<<64, 256, 0, stream>>>(x, wqP, wkP, wvP, wxoP, wx1P, wx2P,
                                        bq, bk, bv, bxo, bx1, bx2, gnx, bnx,
                                        Qb, Kb, out);

    // ---- fused e-path ----
    epath_mfma<<<4096, 256, 0, stream>>>(e, Qb, Kb, wemP, weaP, weoP, we1P, we2P,
                                         bem, bea, beo, be1, be2, gne, bne,
                                         out + 262144);
}

// Round 6
// 357.709 us; speedup vs baseline: 5.2191x; 1.0841x over previous
//
#include <hip/hip_runtime.h>

// ---------------------------------------------------------------------------
// B=8, N=128, XD=256, ED=128, H=8, DF=32, FFX=1024, FFE=512. All I/O fp32.
// softmax over axis=1 + (attn*V).sum(1) collapses to V => newX = (x@wv+bv)@wxo+bxo.
// bf16 MFMA 16x16x32, fp32 accumulate. Verified layouts (rounds 3-5):
//   A-frag: lane holds A[m=lane&15][k=(lane>>4)*8 + j], j=0..7
//   B-frag: lane holds B[k=(lane>>4)*8+j][n=lane&15]  (pre-packed contiguous)
//   C/D   : col=lane&15, row=(lane>>4)*4 + reg
// Round 6: 3 launches (pack_all, qk_gemm, fused_main). fused_main blocks 0..63
// run the x-path remainder (V/newX/LN/FF/LN) concurrently under the 4096
// e-path blocks. Stage-B q*k prefetched to registers; p-loops unroll 2.
// ---------------------------------------------------------------------------

#define RSQRT_DF 0.17677669529663687f  // 1/sqrt(32)

typedef __attribute__((ext_vector_type(8))) short short8;
typedef __attribute__((ext_vector_type(4))) short short4v;
typedef __attribute__((ext_vector_type(4))) float f32x4;

__device__ __forceinline__ short f2bs(float f) {  // fp32->bf16 bits, RNE
    unsigned u = __float_as_uint(f);
    unsigned r = u + 0x7FFFu + ((u >> 16) & 1u);
    return (short)(r >> 16);
}
__device__ __forceinline__ float bs2f(short s) {  // bf16 bits->fp32
    return __uint_as_float(((unsigned)(unsigned short)s) << 16);
}

// ---------------- single-launch weight pack (all 11 weights) ----------------
struct PackArgs {
    const float* W[11];
    short* Wp[11];
    int kdiv[11];   // K/32
    int N[11];
    int start[12];  // prefix sums of per-weight group counts; start[11]=total
};

__global__ __launch_bounds__(256) void pack_all(PackArgs pa) {
    int g = blockIdx.x * 256 + threadIdx.x;
    if (g >= pa.start[11]) return;
    int i = 0;
    while (g >= pa.start[i + 1]) ++i;
    int local = g - pa.start[i];
    int kdiv = pa.kdiv[i], N = pa.N[i];
    int lane = local & 63, rest = local >> 6;
    int kb = rest % kdiv, nt = rest / kdiv;
    int n = nt * 16 + (lane & 15);
    int k0 = kb * 32 + ((lane >> 4) << 3);
    const float* W = pa.W[i];
    short8 v;
#pragma unroll
    for (int j = 0; j < 8; ++j) v[j] = f2bs(W[(size_t)(k0 + j) * N + n]);
    *(short8*)(pa.Wp[i] + (size_t)local * 8) = v;
}

// ---------------- Q/K GEMM (feeds e-path) ----------------------------------
// 128 blocks: bidx&63 = m-tile (16 rows), bidx>>6 = 0:Q / 1:K.
__global__ __launch_bounds__(256) void qk_gemm(
    const float* __restrict__ x,
    const short* __restrict__ wqP, const short* __restrict__ wkP,
    const float* __restrict__ bq, const float* __restrict__ bk,
    float* __restrict__ Qb, float* __restrict__ Kb) {
    __shared__ short sXb[16 * 264];
    const int t = threadIdx.x, wave = t >> 6, lane = t & 63;
    const int quad = lane >> 4, l15 = lane & 15;
    const int m0 = (blockIdx.x & 63) * 16;
    const int isK = blockIdx.x >> 6;
    const short* wP = isK ? wkP : wqP;
    const float* bp = isK ? bk : bq;
    float* outp = isK ? Kb : Qb;

    const float4* x4 = (const float4*)(x + (size_t)m0 * 256);
    for (int g = t; g < 1024; g += 256) {
        float4 v = x4[g];
        int row = g >> 6, col4 = (g & 63) * 4;
        short4v sv = {f2bs(v.x), f2bs(v.y), f2bs(v.z), f2bs(v.w)};
        *(short4v*)(sXb + row * 264 + col4) = sv;
    }
    __syncthreads();

#pragma unroll 2
    for (int p = 0; p < 4; ++p) {
        int nt = wave * 4 + p;
        f32x4 acc = (f32x4){0.f, 0.f, 0.f, 0.f};
        const short* aB = sXb + l15 * 264 + quad * 8;
        const short* bB = wP + ((size_t)(nt * 8) * 64 + lane) * 8;
#pragma unroll
        for (int kb = 0; kb < 8; ++kb) {
            short8 a = *(const short8*)(aB + kb * 32);
            short8 w = *(const short8*)(bB + (size_t)kb * 512);
            acc = __builtin_amdgcn_mfma_f32_16x16x32_bf16(a, w, acc, 0, 0, 0);
        }
        int col = nt * 16 + l15;
        float bvv = bp[col];
#pragma unroll
        for (int r = 0; r < 4; ++r)
            outp[(size_t)(m0 + quad * 4 + r) * 256 + col] = acc[r] + bvv;
    }
}

// ---------------- fused main: 64 x-rest blocks + 4096 e-path blocks --------
// Shared LDS budget 51200 B -> 3 blocks/CU (153600 <= 163840).
// e-path LDS: sEb@0 8704 | sTb@8704 8704 | R2@17408 16896 (sR->sH1half) |
//             R3@34304 16896 (sYb->sH2)                      = 51200
// x-rest LDS: sXb@0 8448 | sVb@8448 8448 (->sH2x) | sTbx@16896 8448 |
//             R@25344 16640 (sRx->sH1x->sH2x? no: sH2x aliases R after E) = 41984
__global__ __launch_bounds__(256, 3) void fused_main(
    const float* __restrict__ x, const float* __restrict__ e,
    const float* __restrict__ Qb, const float* __restrict__ Kb,
    const short* __restrict__ wvP, const short* __restrict__ wxoP,
    const short* __restrict__ wx1P, const short* __restrict__ wx2P,
    const short* __restrict__ wemP, const short* __restrict__ weaP,
    const short* __restrict__ weoP, const short* __restrict__ we1P,
    const short* __restrict__ we2P,
    const float* __restrict__ bv, const float* __restrict__ bxo,
    const float* __restrict__ bx1, const float* __restrict__ bx2,
    const float* __restrict__ bem, const float* __restrict__ bea,
    const float* __restrict__ beo, const float* __restrict__ be1,
    const float* __restrict__ be2,
    const float* __restrict__ gnx, const float* __restrict__ bnx,
    const float* __restrict__ gne, const float* __restrict__ bne,
    float* __restrict__ xout, float* __restrict__ eout) {
    __shared__ __align__(16) char ldsbuf[51200];
    const int t = threadIdx.x, wave = t >> 6, lane = t & 63;
    const int quad = lane >> 4, l15 = lane & 15;

    if (blockIdx.x < 64) {
        // ================= x-path remainder (16 rows per block) =============
        short* sXb = (short*)ldsbuf;               // [16][264] bf16 x (A + residual)
        short* sVb = (short*)(ldsbuf + 8448);      // [16][264] V bf16
        short* sTbx = (short*)(ldsbuf + 16896);    // [16][264] LN1 out
        float* sRx = (float*)(ldsbuf + 25344);     // [16][260] newX fp32
        short* sH1x = (short*)(ldsbuf + 25344);    // [16][520] (alias) H1 half
        float* sH2x = (float*)(ldsbuf + 25344);    // [16][260] (alias) H2
        const int m0 = blockIdx.x * 16;

        const float4* x4 = (const float4*)(x + (size_t)m0 * 256);
        for (int g = t; g < 1024; g += 256) {
            float4 v = x4[g];
            int row = g >> 6, col4 = (g & 63) * 4;
            short4v sv = {f2bs(v.x), f2bs(v.y), f2bs(v.z), f2bs(v.w)};
            *(short4v*)(sXb + row * 264 + col4) = sv;
        }
        __syncthreads();

        // V = x @ wv + bv -> sVb bf16
#pragma unroll 2
        for (int p = 0; p < 4; ++p) {
            int nt = wave * 4 + p;
            f32x4 acc = (f32x4){0.f, 0.f, 0.f, 0.f};
            const short* aB = sXb + l15 * 264 + quad * 8;
            const short* bB = wvP + ((size_t)(nt * 8) * 64 + lane) * 8;
#pragma unroll
            for (int kb = 0; kb < 8; ++kb) {
                short8 a = *(const short8*)(aB + kb * 32);
                short8 w = *(const short8*)(bB + (size_t)kb * 512);
                acc = __builtin_amdgcn_mfma_f32_16x16x32_bf16(a, w, acc, 0, 0, 0);
            }
            int col = nt * 16 + l15;
            float bvv = bv[col];
#pragma unroll
            for (int r = 0; r < 4; ++r)
                sVb[(quad * 4 + r) * 264 + col] = f2bs(acc[r] + bvv);
        }
        __syncthreads();

        // newX = V @ wxo + bxo -> sRx fp32
#pragma unroll 2
        for (int p = 0; p < 4; ++p) {
            int nt = wave * 4 + p;
            f32x4 acc = (f32x4){0.f, 0.f, 0.f, 0.f};
            const short* aB = sVb + l15 * 264 + quad * 8;
            const short* bB = wxoP + ((size_t)(nt * 8) * 64 + lane) * 8;
#pragma unroll
            for (int kb = 0; kb < 8; ++kb) {
                short8 a = *(const short8*)(aB + kb * 32);
                short8 w = *(const short8*)(bB + (size_t)kb * 512);
                acc = __builtin_amdgcn_mfma_f32_16x16x32_bf16(a, w, acc, 0, 0, 0);
            }
            int col = nt * 16 + l15;
            float bvv = bxo[col];
#pragma unroll
            for (int r = 0; r < 4; ++r)
                sRx[(quad * 4 + r) * 260 + col] = acc[r] + bvv;
        }
        __syncthreads();

        // LN1 -> sTbx bf16
        for (int rr = 0; rr < 4; ++rr) {
            int row = wave * 4 + rr;
            float v[4];
            float s1 = 0.f, s2 = 0.f;
#pragma unroll
            for (int k = 0; k < 4; ++k) {
                v[k] = bs2f(sXb[row * 264 + lane + 64 * k]) + sRx[row * 260 + lane + 64 * k];
                s1 += v[k]; s2 += v[k] * v[k];
            }
            for (int off = 32; off; off >>= 1) {
                s1 += __shfl_down(s1, off);
                s2 += __shfl_down(s2, off);
            }
            s1 = __shfl(s1, 0); s2 = __shfl(s2, 0);
            float mean = s1 * (1.f / 256.f);
            float var = s2 * (1.f / 256.f) - mean * mean;
            float rstd = rsqrtf(var + 1e-5f);
#pragma unroll
            for (int k = 0; k < 4; ++k)
                sTbx[row * 264 + lane + 64 * k] =
                    f2bs((v[k] - mean) * rstd * gnx[lane + 64 * k] + bnx[lane + 64 * k]);
        }
        __syncthreads();

        // FF in two 512-col halves; H2 accumulated in registers.
        f32x4 accE[4];
#pragma unroll
        for (int p = 0; p < 4; ++p) accE[p] = (f32x4){0.f, 0.f, 0.f, 0.f};
        for (int half = 0; half < 2; ++half) {
            // H1 half = relu(T @ wx1[:, half*512:+512] + bx1)
#pragma unroll 2
            for (int p = 0; p < 8; ++p) {
                int ntg = half * 32 + wave * 8 + p;
                int coll = (wave * 8 + p) * 16 + l15;
                f32x4 acc = (f32x4){0.f, 0.f, 0.f, 0.f};
                const short* aB = sTbx + l15 * 264 + quad * 8;
                const short* bB = wx1P + ((size_t)(ntg * 8) * 64 + lane) * 8;
#pragma unroll
                for (int kb = 0; kb < 8; ++kb) {
                    short8 a = *(const short8*)(aB + kb * 32);
                    short8 w = *(const short8*)(bB + (size_t)kb * 512);
                    acc = __builtin_amdgcn_mfma_f32_16x16x32_bf16(a, w, acc, 0, 0, 0);
                }
                float bvv = bx1[ntg * 16 + l15];
#pragma unroll
                for (int r = 0; r < 4; ++r)
                    sH1x[(quad * 4 + r) * 520 + coll] = f2bs(fmaxf(acc[r] + bvv, 0.f));
            }
            __syncthreads();
            // H2 += H1half @ wx2[half*512:+512, :]
#pragma unroll 2
            for (int p = 0; p < 4; ++p) {
                int nt = wave * 4 + p;
                const short* aB = sH1x + l15 * 520 + quad * 8;
                const short* bB = wx2P + ((size_t)(nt * 32 + half * 16) * 64 + lane) * 8;
#pragma unroll
                for (int kb = 0; kb < 16; ++kb) {
                    short8 a = *(const short8*)(aB + kb * 32);
                    short8 w = *(const short8*)(bB + (size_t)kb * 512);
                    accE[p] = __builtin_amdgcn_mfma_f32_16x16x32_bf16(a, w, accE[p], 0, 0, 0);
                }
            }
            __syncthreads();
        }
        // H2 epilogue -> sH2x (sH1x dead after the post-E barrier)
#pragma unroll
        for (int p = 0; p < 4; ++p) {
            int nt = wave * 4 + p;
            int col = nt * 16 + l15;
            float bvv = bx2[col];
#pragma unroll
            for (int r = 0; r < 4; ++r)
                sH2x[(quad * 4 + r) * 260 + col] = accE[p][r] + bvv;
        }
        __syncthreads();

        // LN2 -> xout
        for (int rr = 0; rr < 4; ++rr) {
            int row = wave * 4 + rr;
            float v[4];
            float s1 = 0.f, s2 = 0.f;
#pragma unroll
            for (int k = 0; k < 4; ++k) {
                v[k] = bs2f(sXb[row * 264 + lane + 64 * k]) + sH2x[row * 260 + lane + 64 * k];
                s1 += v[k]; s2 += v[k] * v[k];
            }
            for (int off = 32; off; off >>= 1) {
                s1 += __shfl_down(s1, off);
                s2 += __shfl_down(s2, off);
            }
            s1 = __shfl(s1, 0); s2 = __shfl(s2, 0);
            float mean = s1 * (1.f / 256.f);
            float var = s2 * (1.f / 256.f) - mean * mean;
            float rstd = rsqrtf(var + 1e-5f);
#pragma unroll
            for (int k = 0; k < 4; ++k)
                xout[(size_t)(m0 + row) * 256 + lane + 64 * k] =
                    (v[k] - mean) * rstd * gnx[lane + 64 * k] + bnx[lane + 64 * k];
        }
        return;
    }

    // ==================== e-path (32 rows per block) ========================
    short* sEb = (short*)ldsbuf;               // [32][136] bf16 e (A + residual)
    short* sTb = (short*)(ldsbuf + 8704);      // [32][136] LN1 out
    float* sR  = (float*)(ldsbuf + 17408);     // [32][132] newE
    short* sH1 = (short*)(ldsbuf + 17408);     // [32][264] (alias) H1 half
    short* sYb = (short*)(ldsbuf + 34304);     // [32][264] Y bf16
    float* sH2 = (float*)(ldsbuf + 34304);     // [32][132] (alias) FF2 out

    const int r0 = (blockIdx.x - 64) * 32;
    const int b = r0 >> 14;
    const int j0 = r0 & 127;  // 32 | 128 -> same (b,i) for the whole block

    float g0 = gne[lane], g1 = gne[lane + 64];
    float bn0 = bne[lane], bn1 = bne[lane + 64];

    // ---- prefetch q*k for this wave's 8 stage-B positions (global, pre-barrier)
    float qk[8][4];
#pragma unroll
    for (int p = 0; p < 8; ++p) {
        int pos = wave * 8 + p, mt = pos >> 4, nt = pos & 15;
        int col = nt * 16 + l15;
        float q = Qb[(size_t)(r0 >> 7) * 256 + col] * RSQRT_DF;
        const float* kp = Kb + (size_t)((b << 7) + j0 + mt * 16 + quad * 4) * 256 + col;
#pragma unroll
        for (int r = 0; r < 4; ++r) qk[p][r] = q * kp[(size_t)r * 256];
    }

    // ---- load e tile (bf16) ----
    {
        const float4* e4 = (const float4*)(e + (size_t)r0 * 128);
        for (int g = t; g < 1024; g += 256) {
            float4 v = e4[g];
            int row = g >> 5, col4 = (g & 31) * 4;
            short4v sv = {f2bs(v.x), f2bs(v.y), f2bs(v.z), f2bs(v.w)};
            *(short4v*)(sEb + row * 136 + col4) = sv;
        }
    }
    __syncthreads();

    // ---- Stage B: E1/E2 MFMA; Y = qk*(E1+1)+E2 -> sYb ----
#pragma unroll 2
    for (int p = 0; p < 8; ++p) {
        int pos = wave * 8 + p, mt = pos >> 4, nt = pos & 15;
        f32x4 a1 = (f32x4){0.f, 0.f, 0.f, 0.f}, a2 = (f32x4){0.f, 0.f, 0.f, 0.f};
        const short* aB = sEb + (mt * 16 + l15) * 136 + quad * 8;
        const short* b1 = wemP + ((size_t)(nt * 4) * 64 + lane) * 8;
        const short* b2 = weaP + ((size_t)(nt * 4) * 64 + lane) * 8;
#pragma unroll
        for (int kb = 0; kb < 4; ++kb) {
            short8 a = *(const short8*)(aB + kb * 32);
            short8 w1 = *(const short8*)(b1 + kb * 512);
            short8 w2 = *(const short8*)(b2 + kb * 512);
            a1 = __builtin_amdgcn_mfma_f32_16x16x32_bf16(a, w1, a1, 0, 0, 0);
            a2 = __builtin_amdgcn_mfma_f32_16x16x32_bf16(a, w2, a2, 0, 0, 0);
        }
        int col = nt * 16 + l15;
        float bm = bem[col], ba = bea[col];
#pragma unroll
        for (int r = 0; r < 4; ++r) {
            int row = mt * 16 + quad * 4 + r;
            float y = qk[p][r] * (a1[r] + bm + 1.0f) + (a2[r] + ba);
            sYb[row * 264 + col] = f2bs(y);
        }
    }
    __syncthreads();

    // ---- Stage C: newE = Y @ weo + beo -> sR ----
#pragma unroll 2
    for (int p = 0; p < 4; ++p) {
        int pos = wave * 4 + p, mt = pos >> 3, nt = pos & 7;
        f32x4 acc = (f32x4){0.f, 0.f, 0.f, 0.f};
        const short* aB = sYb + (mt * 16 + l15) * 264 + quad * 8;
        const short* bB = weoP + ((size_t)(nt * 8) * 64 + lane) * 8;
#pragma unroll
        for (int kb = 0; kb < 8; ++kb) {
            short8 a = *(const short8*)(aB + kb * 32);
            short8 w = *(const short8*)(bB + kb * 512);
            acc = __builtin_amdgcn_mfma_f32_16x16x32_bf16(a, w, acc, 0, 0, 0);
        }
        int col = nt * 16 + l15;
        float bo = beo[col];
#pragma unroll
        for (int r = 0; r < 4; ++r)
            sR[(mt * 16 + quad * 4 + r) * 132 + col] = acc[r] + bo;
    }
    __syncthreads();

    // ---- LN1: sTb = bf16(LN(e + newE)*gne + bne) ----
    for (int rr = 0; rr < 8; ++rr) {
        int row = wave * 8 + rr;
        float v0 = bs2f(sEb[row * 136 + lane]) + sR[row * 132 + lane];
        float v1 = bs2f(sEb[row * 136 + lane + 64]) + sR[row * 132 + lane + 64];
        float s1 = v0 + v1, s2 = v0 * v0 + v1 * v1;
        for (int off = 32; off; off >>= 1) {
            s1 += __shfl_down(s1, off);
            s2 += __shfl_down(s2, off);
        }
        s1 = __shfl(s1, 0); s2 = __shfl(s2, 0);
        float mean = s1 * 0.0078125f;
        float var = s2 * 0.0078125f - mean * mean;
        float rstd = rsqrtf(var + 1e-5f);
        sTb[row * 136 + lane]      = f2bs((v0 - mean) * rstd * g0 + bn0);
        sTb[row * 136 + lane + 64] = f2bs((v1 - mean) * rstd * g1 + bn1);
    }
    __syncthreads();

    // ---- FF in two 256-col halves; H2 accumulated in registers ----
    f32x4 accE[4];
#pragma unroll
    for (int p = 0; p < 4; ++p) accE[p] = (f32x4){0.f, 0.f, 0.f, 0.f};

    for (int half = 0; half < 2; ++half) {
#pragma unroll 2
        for (int p = 0; p < 8; ++p) {
            int pos = wave * 8 + p, mt = pos >> 4, ntl = pos & 15;
            int nt = half * 16 + ntl;
            f32x4 acc = (f32x4){0.f, 0.f, 0.f, 0.f};
            const short* aB = sTb + (mt * 16 + l15) * 136 + quad * 8;
            const short* bB = we1P + ((size_t)(nt * 4) * 64 + lane) * 8;
#pragma unroll
            for (int kb = 0; kb < 4; ++kb) {
                short8 a = *(const short8*)(aB + kb * 32);
                short8 w = *(const short8*)(bB + kb * 512);
                acc = __builtin_amdgcn_mfma_f32_16x16x32_bf16(a, w, acc, 0, 0, 0);
            }
            int coll = ntl * 16 + l15;
            float bvv = be1[nt * 16 + l15];
#pragma unroll
            for (int r = 0; r < 4; ++r)
                sH1[(mt * 16 + quad * 4 + r) * 264 + coll] =
                    f2bs(fmaxf(acc[r] + bvv, 0.f));
        }
        __syncthreads();
#pragma unroll 2
        for (int p = 0; p < 4; ++p) {
            int pos = wave * 4 + p, mt = pos >> 3, nt = pos & 7;
            const short* aB = sH1 + (mt * 16 + l15) * 264 + quad * 8;
            const short* bB = we2P + ((size_t)(nt * 16 + half * 8) * 64 + lane) * 8;
#pragma unroll
            for (int kb = 0; kb < 8; ++kb) {
                short8 a = *(const short8*)(aB + kb * 32);
                short8 w = *(const short8*)(bB + kb * 512);
                accE[p] = __builtin_amdgcn_mfma_f32_16x16x32_bf16(a, w, accE[p], 0, 0, 0);
            }
        }
        __syncthreads();
    }
#pragma unroll
    for (int p = 0; p < 4; ++p) {
        int pos = wave * 4 + p, mt = pos >> 3, nt = pos & 7;
        int col = nt * 16 + l15;
        float bvv = be2[col];
#pragma unroll
        for (int r = 0; r < 4; ++r)
            sH2[(mt * 16 + quad * 4 + r) * 132 + col] = accE[p][r] + bvv;
    }
    __syncthreads();

    // ---- LN2 -> global ----
    for (int rr = 0; rr < 8; ++rr) {
        int row = wave * 8 + rr;
        float v0 = bs2f(sEb[row * 136 + lane]) + sH2[row * 132 + lane];
        float v1 = bs2f(sEb[row * 136 + lane + 64]) + sH2[row * 132 + lane + 64];
        float s1 = v0 + v1, s2 = v0 * v0 + v1 * v1;
        for (int off = 32; off; off >>= 1) {
            s1 += __shfl_down(s1, off);
            s2 += __shfl_down(s2, off);
        }
        s1 = __shfl(s1, 0); s2 = __shfl(s2, 0);
        float mean = s1 * 0.0078125f;
        float var = s2 * 0.0078125f - mean * mean;
        float rstd = rsqrtf(var + 1e-5f);
        size_t o = (size_t)(r0 + row) * 128;
        eout[o + lane]      = (v0 - mean) * rstd * g0 + bn0;
        eout[o + lane + 64] = (v1 - mean) * rstd * g1 + bn1;
    }
}

extern "C" void kernel_launch(void* const* d_in, const int* in_sizes, int n_in,
                              void* d_out, int out_size, void* d_ws, size_t ws_size,
                              hipStream_t stream) {
    const float* x   = (const float*)d_in[0];
    const float* e   = (const float*)d_in[1];
    const float* wq  = (const float*)d_in[2];
    const float* wk  = (const float*)d_in[3];
    const float* wv  = (const float*)d_in[4];
    const float* wem = (const float*)d_in[5];
    const float* wea = (const float*)d_in[6];
    const float* wxo = (const float*)d_in[7];
    const float* weo = (const float*)d_in[8];
    const float* wx1 = (const float*)d_in[9];
    const float* wx2 = (const float*)d_in[10];
    const float* we1 = (const float*)d_in[11];
    const float* we2 = (const float*)d_in[12];
    const float* bq  = (const float*)d_in[13];
    const float* bk  = (const float*)d_in[14];
    const float* bv  = (const float*)d_in[15];
    const float* bem = (const float*)d_in[16];
    const float* bea = (const float*)d_in[17];
    const float* bxo = (const float*)d_in[18];
    const float* beo = (const float*)d_in[19];
    const float* bx1 = (const float*)d_in[20];
    const float* bx2 = (const float*)d_in[21];
    const float* be1 = (const float*)d_in[22];
    const float* be2 = (const float*)d_in[23];
    const float* gnx = (const float*)d_in[24];
    const float* bnx = (const float*)d_in[25];
    const float* gne = (const float*)d_in[26];
    const float* bne = (const float*)d_in[27];

    float* out = (float*)d_out;  // x_out (262144) then e_out (16777216)

    float* ws = (float*)d_ws;
    float* Qb = ws;               // 262144 f32
    float* Kb = Qb + 262144;      // 262144 f32
    short* base = (short*)(Kb + 262144);
    short* wqP  = base;           // 65536
    short* wkP  = wqP + 65536;
    short* wvP  = wkP + 65536;
    short* wxoP = wvP + 65536;
    short* wx1P = wxoP + 65536;   // 262144
    short* wx2P = wx1P + 262144;  // 262144
    short* wemP = wx2P + 262144;  // 32768
    short* weaP = wemP + 32768;
    short* weoP = weaP + 32768;
    short* we1P = weoP + 32768;   // 65536
    short* we2P = we1P + 65536;   // 65536

    // ---- one pack launch for all 11 weights ----
    PackArgs pa;
    const float* Ws[11] = {wq, wk, wv, wxo, wx1, wx2, wem, wea, weo, we1, we2};
    short* Wps[11] = {wqP, wkP, wvP, wxoP, wx1P, wx2P, wemP, weaP, weoP, we1P, we2P};
    int Ks[11] = {256, 256, 256, 256, 256, 1024, 128, 128, 256, 128, 512};
    int Ns[11] = {256, 256, 256, 256, 1024, 256, 256, 256, 128, 512, 128};
    int acc = 0;
    for (int i = 0; i < 11; ++i) {
        pa.W[i] = Ws[i];
        pa.Wp[i] = Wps[i];
        pa.kdiv[i] = Ks[i] >> 5;
        pa.N[i] = Ns[i];
        pa.start[i] = acc;
        acc += (Ns[i] >> 4) * (Ks[i] >> 5) * 64;
    }
    pa.start[11] = acc;
    pack_all<<<(acc + 255) / 256, 256, 0, stream>>>(pa);

    // ---- Q/K GEMM (only cross-path dependency) ----
    qk_gemm<<<128, 256, 0, stream>>>(x, wqP, wkP, bq, bk, Qb, Kb);

    // ---- fused main: 64 x-rest blocks (first, overlap) + 4096 e-path ----
    fused_main<<<4160, 256, 0, stream>>>(
        x, e, Qb, Kb, wvP, wxoP, wx1P, wx2P, wemP, weaP, weoP, we1P, we2P,
        bv, bxo, bx1, bx2, bem, bea, beo, be1, be2,
        gnx, bnx, gne, bne, out, out + 262144);
}